// Round 8
// baseline (1045.360 us; speedup 1.0000x reference)
//
#include <hip/hip_runtime.h>
#include <hip/hip_bf16.h>

#define HWs 50176      // 224*224
#define WID 224
#define OHW 200704     // 448*448

// ---------------- K0: weights OIHW -> wt2[g][ic][o*9+t], g = oc/4 group (25 per layer).
// Per-wave 36-float slices are contiguous -> wave-uniform s_load in k_conv.
__global__ void k_wt(const float* __restrict__ w_head, const float* __restrict__ w_blk,
                     float* __restrict__ wt2) {
  int l = blockIdx.y;
  int i = blockIdx.x * 256 + threadIdx.x;
  if (i >= 90000) return;
  const float* src = (l == 0) ? w_head : (w_blk + (l - 1) * 90000);
  int g = i / 3600, r2 = i - g * 3600;
  int ic = r2 / 36, k = r2 - ic * 36;
  int o = k / 9, t = k - o * 9;
  wt2[l * 90000 + i] = src[(4 * g + o) * 900 + ic * 9 + t];
}

// ---------------- K0b: xlast = b_last (re-init every launch; k_post atomically accumulates)
__global__ void k_binit(const float* __restrict__ blast, float* __restrict__ xlast) {
  int p = blockIdx.x * 256 + threadIdx.x;
  xlast[(size_t)blockIdx.y * HWs + p] = blast[blockIdx.y];
}

// ---------------- K1: bilinear warp + concat, channel-split for occupancy.
__global__ void k_warp(const float* __restrict__ f0, const float* __restrict__ f1,
                       const float* __restrict__ fd, const float* __restrict__ fl,
                       float* __restrict__ xin) {
  int p = blockIdx.x * 256 + threadIdx.x;
  int yq = blockIdx.y;
  int y = p / WID, x = p - y * WID;
  float fx0 = fl[p];
  float fy0 = fl[HWs + p];
  float fx1 = fl[2 * HWs + p];
  float fy1 = fl[3 * HWs + p];

  #pragma unroll
  for (int img = 0; img < 2; ++img) {
    const float* src = img ? f1 : f0;
    float fx = img ? fx1 : fx0;
    float fy = img ? fy1 : fy0;
    float px = (float)x + fx, py = (float)y + fy;
    float x0f = floorf(px), y0f = floorf(py);
    float wx = px - x0f, wy = py - y0f;
    int x0 = (int)fminf(fmaxf(x0f,       0.f), 223.f);
    int x1 = (int)fminf(fmaxf(x0f + 1.f, 0.f), 223.f);
    int y0 = (int)fminf(fmaxf(y0f,       0.f), 223.f);
    int y1 = (int)fminf(fmaxf(y0f + 1.f, 0.f), 223.f);
    float w00 = (1.f - wx) * (1.f - wy), w01 = wx * (1.f - wy);
    float w10 = (1.f - wx) * wy,         w11 = wx * wy;
    int i00 = y0 * WID + x0, i01 = y0 * WID + x1;
    int i10 = y1 * WID + x0, i11 = y1 * WID + x1;
    float* dst = xin + img * 32 * HWs;
    for (int c = yq * 8; c < yq * 8 + 8; ++c) {
      const float* pl = src + c * HWs;
      dst[c * HWs + p] = w00 * pl[i00] + w01 * pl[i01]
                       + w10 * pl[i10] + w11 * pl[i11];
    }
  }
  for (int c = yq * 8; c < yq * 8 + 8; ++c)
    xin[(64 + c) * HWs + p] = fd[c * HWs + p];
  if (yq == 0) {
    xin[96 * HWs + p] = fx0; xin[97 * HWs + p] = fy0;
    xin[98 * HWs + p] = fx1; xin[99 * HWs + p] = fy1;
  }
}

// ---------------- K2: conv3x3 partial, SGPR weights + LDS patch only.
// grid (10,7,14), block 320 = 5 waves. bx: slice = bx%5 (20 oc), half = bx/5 (50 ic).
// Wave w owns oc [4*(5*slice+w) .. +4) -> weights are WAVE-UNIFORM s_loads (36/ic).
// Block px tile 32 cols x 16 rows; lane: r=lane>>2 (row), c8=lane&3 (8-col strip).
// LDS: patch only, 10 ic x 18 rows x stride 36 = 25.9 KB. Patch b128 reads start at
// banks (4R+8c)%32 — same distribution as stride-1 baseline -> conflict-free.
// Per thread*ic: 288 FMA vs 9 LDS reads -> FMA-bound.
__global__ __launch_bounds__(320) void k_conv(
    const float* __restrict__ in, const float* __restrict__ wt2,
    float* __restrict__ pbase) {
  __shared__ __align__(16) float patch[6480];      // [10 icl][18 ry][stride 36]
  int tid = threadIdx.x;
  int slice = blockIdx.x % 5, half = blockIdx.x / 5;
  int colbase = blockIdx.y * 32, rowbase = blockIdx.z * 16;
  int icz = half * 50;
  float* pout = pbase + (size_t)half * 100 * HWs;

  int lane = tid & 63;
  int wv = __builtin_amdgcn_readfirstlane(tid >> 6);   // wave id 0..4, uniform
  int g = slice * 5 + wv;                              // oc-group 0..24, uniform
  const float* wbase = wt2 + (size_t)g * 100 * 36;     // wave-uniform pointer
  int r = lane >> 2, c8 = lane & 3;

  float acc[4][8];
  #pragma unroll
  for (int o = 0; o < 4; ++o)
    #pragma unroll
    for (int p = 0; p < 8; ++p) acc[o][p] = 0.f;

  for (int ic0 = 0; ic0 < 50; ic0 += 10) {
    __syncthreads();
    // stage 10 ic x 18 x 34 patch (cols 34-35 pad, never read)
    for (int j = tid; j < 6480; j += 320) {
      int icl = j / 648, rem = j - icl * 648;
      int ry = rem / 36, rx = rem - ry * 36;
      if (rx < 34) {
        int gy = rowbase - 1 + ry, gx = colbase - 1 + rx;
        float v = 0.f;
        if ((unsigned)gy < 224u && (unsigned)gx < 224u)
          v = in[(size_t)(icz + ic0 + icl) * HWs + gy * WID + gx];
        patch[j] = v;
      }
    }
    __syncthreads();

    for (int icl = 0; icl < 10; ++icl) {
      const float* ws = wbase + (size_t)(icz + ic0 + icl) * 36;  // uniform -> s_load
      float rr[3][10];
      #pragma unroll
      for (int dy = 0; dy < 3; ++dy) {
        const float* prow = &patch[icl * 648 + (r + dy) * 36 + c8 * 8];
        float4 a = *(const float4*)prow;
        float4 b = *(const float4*)(prow + 4);
        float2 c = *(const float2*)(prow + 8);
        rr[dy][0] = a.x; rr[dy][1] = a.y; rr[dy][2] = a.z; rr[dy][3] = a.w;
        rr[dy][4] = b.x; rr[dy][5] = b.y; rr[dy][6] = b.z; rr[dy][7] = b.w;
        rr[dy][8] = c.x; rr[dy][9] = c.y;
      }
      #pragma unroll
      for (int o = 0; o < 4; ++o) {
        #pragma unroll
        for (int dy = 0; dy < 3; ++dy) {
          #pragma unroll
          for (int dx = 0; dx < 3; ++dx) {
            float w = ws[o * 9 + dy * 3 + dx];
            #pragma unroll
            for (int p = 0; p < 8; ++p)
              acc[o][p] = fmaf(w, rr[dy][dx + p], acc[o][p]);
          }
        }
      }
    }
  }

  int gy = rowbase + r, gx0 = colbase + c8 * 8;
  #pragma unroll
  for (int o = 0; o < 4; ++o) {
    float* dst = pout + (size_t)(4 * g + o) * HWs + gy * WID + gx0;
    *(float4*)(dst)     = make_float4(acc[o][0], acc[o][1], acc[o][2], acc[o][3]);
    *(float4*)(dst + 4) = make_float4(acc[o][4], acc[o][5], acc[o][6], acc[o][7]);
  }
}

// ---------------- K3: fused 2-partial combine + PReLU*mask + activation write
// + einsum contribution via atomicAdd into xlast (seeded with b_last by k_binit).
__global__ void k_post(const float* __restrict__ pA, const float* __restrict__ pB,
                       const float* __restrict__ avec, const float* __restrict__ mask,
                       const float* __restrict__ wlast,
                       float* __restrict__ xact, float* __restrict__ xlast,
                       int base) {
  __shared__ __align__(16) float wl[25 * 36];      // [il][o] for this slice
  __shared__ float al[25];
  int tid = threadIdx.x;
  int ocq = blockIdx.y;
  for (int j = tid; j < 25 * 36; j += 64) {
    int il = j / 36, o = j - il * 36;
    wl[j] = wlast[o * 500 + base + 25 * ocq + il];
  }
  if (tid < 25) al[tid] = avec[25 * ocq + tid];
  __syncthreads();
  int p = blockIdx.x * 64 + tid;
  float m = mask[p];
  float acc[36];
  #pragma unroll
  for (int o = 0; o < 36; ++o) acc[o] = 0.f;
  for (int il = 0; il < 25; ++il) {
    int oc = 25 * ocq + il;
    float z = pA[oc * HWs + p] + pB[oc * HWs + p];
    float v = (z >= 0.f ? z : al[il] * z) * m;
    xact[oc * HWs + p] = v;
    const float4* wp = (const float4*)&wl[il * 36];
    #pragma unroll
    for (int j = 0; j < 9; ++j) {
      float4 t = wp[j];
      acc[4*j]   += t.x * v;
      acc[4*j+1] += t.y * v;
      acc[4*j+2] += t.z * v;
      acc[4*j+3] += t.w * v;
    }
  }
  #pragma unroll
  for (int o = 0; o < 36; ++o)
    atomicAdd(&xlast[o * HWs + p], acc[o]);
}

// ---------------- K4: smn halves = conv3x3(xlast[4+h*16 .. +16], w_mask), fp64 accum.
__global__ void k_smn(const float* __restrict__ xlast, const float* __restrict__ wmask,
                      const float* __restrict__ bmask, float* __restrict__ smnh) {
  __shared__ float wm[288];                        // [2 oc][16 ic][9]
  int tid = threadIdx.x;
  int h = blockIdx.y;
  for (int j = tid; j < 288; j += 64) {
    int o = j / 144, r = j - o * 144;              // r = icl*9+tap
    wm[j] = wmask[o * 288 + h * 144 + r];
  }
  __syncthreads();
  int p = blockIdx.x * 64 + tid;
  int y = p / WID, x = p - y * WID;
  double a0 = 0.0, a1 = 0.0;
  for (int icl = 0; icl < 16; ++icl) {
    const float* pl = xlast + (size_t)(4 + h * 16 + icl) * HWs;
    #pragma unroll
    for (int dy = -1; dy <= 1; ++dy) {
      int gy = y + dy;
      if ((unsigned)gy < 224u) {
        #pragma unroll
        for (int dx = -1; dx <= 1; ++dx) {
          int gx = x + dx;
          if ((unsigned)gx < 224u) {
            double v = (double)pl[gy * WID + gx];
            int t = (dy + 1) * 3 + (dx + 1);
            a0 += (double)wm[icl * 9 + t] * v;
            a1 += (double)wm[144 + icl * 9 + t] * v;
          }
        }
      }
    }
  }
  if (h == 0) { a0 += (double)bmask[0]; a1 += (double)bmask[1]; }
  smnh[(size_t)(h * 2 + 0) * HWs + p] = (float)a0;
  smnh[(size_t)(h * 2 + 1) * HWs + p] = (float)a1;
}

// ---------------- K5: 2x bilinear upsample (jax.image.resize 'linear') + mask compare
__global__ void k_upsample(const float* __restrict__ xlast, const float* __restrict__ smnh,
                           const float* __restrict__ smask, float* __restrict__ out) {
  int q = blockIdx.x * 256 + threadIdx.x;          // 784*256 == 200704 exact
  int oy = q / 448, ox = q - oy * 448;
  int ky = oy >> 1, kx = ox >> 1;
  int r0, r1, c0, c1; float wy0, wy1, wx0, wx1;
  if (oy & 1) { r0 = ky; r1 = (ky < 223) ? ky + 1 : 223; wy0 = 0.75f; wy1 = 0.25f; }
  else        { r0 = (ky > 0) ? ky - 1 : 0; r1 = ky;     wy0 = 0.25f; wy1 = 0.75f; }
  if (ox & 1) { c0 = kx; c1 = (kx < 223) ? kx + 1 : 223; wx0 = 0.75f; wx1 = 0.25f; }
  else        { c0 = (kx > 0) ? kx - 1 : 0; c1 = kx;     wx0 = 0.25f; wx1 = 0.75f; }
  float w00 = wy0 * wx0, w01 = wy0 * wx1, w10 = wy1 * wx0, w11 = wy1 * wx1;
  int i00 = r0 * WID + c0, i01 = r0 * WID + c1, i10 = r1 * WID + c0, i11 = r1 * WID + c1;
  for (int ch = 0; ch < 36; ++ch) {
    const float* pl = xlast + (size_t)ch * HWs;
    out[(size_t)ch * OHW + q] = w00 * pl[i00] + w01 * pl[i01]
                              + w10 * pl[i10] + w11 * pl[i11];
  }
  const float* sa0 = smnh;                 // oc0 half0 (+bias)
  const float* sa1 = smnh + HWs;           // oc1 half0 (+bias)
  const float* sb0 = smnh + 2 * HWs;       // oc0 half1
  const float* sb1 = smnh + 3 * HWs;       // oc1 half1
  double s0 = (double)w00 * ((double)sa0[i00] + (double)sb0[i00])
            + (double)w01 * ((double)sa0[i01] + (double)sb0[i01])
            + (double)w10 * ((double)sa0[i10] + (double)sb0[i10])
            + (double)w11 * ((double)sa0[i11] + (double)sb0[i11]);
  double s1 = (double)w00 * ((double)sa1[i00] + (double)sb1[i00])
            + (double)w10 * ((double)sa1[i10] + (double)sb1[i10])
            + (double)w01 * ((double)sa1[i01] + (double)sb1[i01])
            + (double)w11 * ((double)sa1[i11] + (double)sb1[i11]);
  float mu = smask[ky * WID + kx];
  out[36 * OHW + q] = (s0 > s1) ? mu : 0.f;
}

extern "C" void kernel_launch(void* const* d_in, const int* in_sizes, int n_in,
                              void* d_out, int out_size, void* d_ws, size_t ws_size,
                              hipStream_t stream) {
  const float* feat0   = (const float*)d_in[0];
  const float* feat1   = (const float*)d_in[1];
  const float* featd   = (const float*)d_in[2];
  const float* flow    = (const float*)d_in[3];
  const float* smask   = (const float*)d_in[4];
  const float* w_head  = (const float*)d_in[5];
  const float* a_head  = (const float*)d_in[6];
  const float* w_blk   = (const float*)d_in[7];
  const float* a_blk   = (const float*)d_in[8];
  const float* w_last  = (const float*)d_in[9];
  const float* b_last  = (const float*)d_in[10];
  const float* w_mask  = (const float*)d_in[11];
  const float* b_mask  = (const float*)d_in[12];

  // ws layout: act0/act1 + partials pA/pB + xlast + smnh(4) + wt2 (~90 MB)
  float* act0  = (float*)d_ws;            // 100 planes
  float* act1  = act0 + 100 * HWs;        // 100 planes
  float* pA    = act1 + 100 * HWs;        // 100 planes
  float* pB    = pA   + 100 * HWs;        // 100 planes
  float* xlast = pB   + 100 * HWs;        // 36 planes
  float* smnh  = xlast + 36 * HWs;        // 4 planes
  float* wt2   = smnh + 4 * HWs;          // 5*90000 floats

  k_wt<<<dim3(352, 5), 256, 0, stream>>>(w_head, w_blk, wt2);
  k_binit<<<dim3(196, 36), 256, 0, stream>>>(b_last, xlast);
  k_warp<<<dim3(196, 4), 256, 0, stream>>>(feat0, feat1, featd, flow, act0);

  dim3 cgrid(10, 7, 14);
  dim3 pgrid(784, 4);
  // head: act0 -> partials -> act1, einsum slice 0
  k_conv<<<cgrid, 320, 0, stream>>>(act0, wt2, pA);
  k_post<<<pgrid, 64, 0, stream>>>(pA, pB, a_head, smask, w_last,
                                   act1, xlast, 0);
  // blocks: ping-pong act1 <-> act0
  float* src = act1; float* dst = act0;
  for (int l = 0; l < 4; ++l) {
    k_conv<<<cgrid, 320, 0, stream>>>(src, wt2 + (l + 1) * 90000, pA);
    k_post<<<pgrid, 64, 0, stream>>>(pA, pB, a_blk + l * 100, smask, w_last,
                                     dst, xlast, (l + 1) * 100);
    float* t = src; src = dst; dst = t;
  }

  k_smn<<<dim3(784, 2), 64, 0, stream>>>(xlast, w_mask, b_mask, smnh);
  k_upsample<<<784, 256, 0, stream>>>(xlast, smnh, smask, (float*)d_out);
}